// Round 4
// baseline (526.154 us; speedup 1.0000x reference)
//
#include <hip/hip_runtime.h>
#include <stdint.h>

typedef unsigned short u16t;
typedef __attribute__((ext_vector_type(8))) short frag8;   // 8 x bf16 (4 VGPRs)
typedef __attribute__((ext_vector_type(4))) float facc4;   // MFMA accumulator

#define S_LEN 2048
#define E_DIM 2048

__device__ __forceinline__ u16t f2bf(float f) {
    union { float f; uint32_t u; } c; c.f = f;
    return (u16t)((c.u + 0x7fffu + ((c.u >> 16) & 1u)) >> 16);  // RNE
}

// ---------------- fp32 -> bf16 conversion (vectorized) ----------------
__global__ __launch_bounds__(256) void cvt_kernel(const float* __restrict__ src,
                                                  u16t* __restrict__ dst, int n4) {
    int i = blockIdx.x * 256 + threadIdx.x;
    if (i >= n4) return;
    float4 v = ((const float4*)src)[i];
    ushort4 o;
    o.x = f2bf(v.x); o.y = f2bf(v.y); o.z = f2bf(v.z); o.w = f2bf(v.w);
    ((ushort4*)dst)[i] = o;
}

// ---------------- async global->LDS, 16B per lane ----------------
__device__ __forceinline__ void gldl16(const u16t* g, u16t* l) {
    __builtin_amdgcn_global_load_lds(
        (__attribute__((address_space(1))) void*)(g),
        (__attribute__((address_space(3))) void*)(l), 16, 0, 0);
}

// ---------------- GEMM core: C[128x256] = A[128xK] * B[256xK]^T ----------------
// 4 waves, each computing a 64x128 sub-tile (4x8 grid of 16x16x32 MFMA).
// BK=64 staged as two 32-col half-tiles. XOR-swizzled LDS layout: 16B chunk c
// of row r lives at physical chunk c ^ ((r>>1)&3)  ->  frag ds_read_b128 hits
// each bank with exactly 2 lanes (free; was 8-way = 2.9x penalty).
__device__ __forceinline__ void gemm_core(const u16t* __restrict__ A,
                                          const u16t* __restrict__ Bw,
                                          u16t* As0, u16t* As1,
                                          u16t* Bs0, u16t* Bs1,
                                          facc4 acc[4][8]) {
    const int t    = threadIdx.x;
    const int lane = t & 63;
    const int wid  = t >> 6;
    const int m16  = lane & 15;
    const int quad = lane >> 4;
    const int sw   = (m16 >> 1) & 3;            // frag-read swizzle
    const int wm   = (wid & 1) * 64;
    const int wn   = (wid >> 1) * 128;
    const size_t bm0 = (size_t)blockIdx.y * 128;
    const size_t bn0 = (size_t)blockIdx.x * 256;

#pragma unroll
    for (int i = 0; i < 4; ++i)
#pragma unroll
        for (int j = 0; j < 8; ++j) acc[i][j] = facc4{0.f, 0.f, 0.f, 0.f};

    const u16t* Ab = A + bm0 * E_DIM;
    const u16t* Bb = Bw + bn0 * E_DIM;

    // staging: element e = waveBase + call*512 + lane*8 ; r = e>>5 ;
    // global chunk fetched = (lane&3) ^ ((r>>1)&3)   (the swizzle)
    const int l8 = lane * 8;
    const int rA0 = ((wid * 1024 + l8) >> 5);
    const int rA1 = rA0 + 16;
    const int rB0 = ((wid * 2048 + l8) >> 5);
    const int rB1 = rB0 + 16, rB2 = rB0 + 32, rB3 = rB0 + 48;
    const int c3 = lane & 3;
    const size_t gA0 = (size_t)rA0 * E_DIM + ((c3 ^ ((rA0 >> 1) & 3)) * 8);
    const size_t gA1 = (size_t)rA1 * E_DIM + ((c3 ^ ((rA1 >> 1) & 3)) * 8);
    const size_t gB0 = (size_t)rB0 * E_DIM + ((c3 ^ ((rB0 >> 1) & 3)) * 8);
    const size_t gB1 = (size_t)rB1 * E_DIM + ((c3 ^ ((rB1 >> 1) & 3)) * 8);
    const size_t gB2 = (size_t)rB2 * E_DIM + ((c3 ^ ((rB2 >> 1) & 3)) * 8);
    const size_t gB3 = (size_t)rB3 * E_DIM + ((c3 ^ ((rB3 >> 1) & 3)) * 8);
    // per-buffer wave-uniform LDS bases (bug fix: Bs1-Bs0 != As1-As0)
    u16t* lA0 = As0 + wid * 1024;
    u16t* lA1 = As1 + wid * 1024;
    u16t* lB0 = Bs0 + wid * 2048;
    u16t* lB1 = Bs1 + wid * 2048;

    for (int k0 = 0; k0 < E_DIM; k0 += 64) {
        __syncthreads();   // previous iter's LDS readers done
        gldl16(Ab + gA0 + k0,      lA0);
        gldl16(Ab + gA1 + k0,      lA0 + 512);
        gldl16(Ab + gA0 + k0 + 32, lA1);
        gldl16(Ab + gA1 + k0 + 32, lA1 + 512);
        gldl16(Bb + gB0 + k0,      lB0);
        gldl16(Bb + gB1 + k0,      lB0 + 512);
        gldl16(Bb + gB2 + k0,      lB0 + 1024);
        gldl16(Bb + gB3 + k0,      lB0 + 1536);
        gldl16(Bb + gB0 + k0 + 32, lB1);
        gldl16(Bb + gB1 + k0 + 32, lB1 + 512);
        gldl16(Bb + gB2 + k0 + 32, lB1 + 1024);
        gldl16(Bb + gB3 + k0 + 32, lB1 + 1536);
        __syncthreads();   // drain vmcnt + barrier

#pragma unroll
        for (int h = 0; h < 2; ++h) {
            const u16t* Ah = h ? As1 : As0;
            const u16t* Bh = h ? Bs1 : Bs0;
            frag8 av[4], bv[8];
#pragma unroll
            for (int i = 0; i < 4; ++i)
                av[i] = *(const frag8*)(Ah + (wm + i * 16 + m16) * 32 + (quad ^ sw) * 8);
#pragma unroll
            for (int j = 0; j < 8; ++j)
                bv[j] = *(const frag8*)(Bh + (wn + j * 16 + m16) * 32 + (quad ^ sw) * 8);
#pragma unroll
            for (int i = 0; i < 4; ++i)
#pragma unroll
                for (int j = 0; j < 8; ++j)
                    acc[i][j] = __builtin_amdgcn_mfma_f32_16x16x32_bf16(
                        av[i], bv[j], acc[i][j], 0, 0, 0);
        }
    }
}

// ---------------- fused QKV projection (+bias, +RoPE for q,k) ----------------
struct QkvArgs {
    const u16t* w[3];
    const float* bias[3];
    u16t* out[3];
};

__global__ __launch_bounds__(256, 2)
void qkv_gemm(const u16t* __restrict__ xb, QkvArgs args,
              const float* __restrict__ fcos, const float* __restrict__ fsin) {
    __shared__ u16t As0[128 * 32], As1[128 * 32];
    __shared__ u16t Bs0[256 * 32], Bs1[256 * 32];
    facc4 acc[4][8];
    const int z = blockIdx.z;
    gemm_core(xb, args.w[z], As0, As1, Bs0, Bs1, acc);

    const int t    = threadIdx.x;
    const int lane = t & 63;
    const int m16  = lane & 15;
    const int quad = lane >> 4;
    const int wid  = t >> 6;
    const int wm   = (wid & 1) * 64;
    const int wn   = (wid >> 1) * 128;
    const int bm0  = blockIdx.y * 128;
    const int bn0  = blockIdx.x * 256;
    const bool rope = (z < 2);
    u16t* out = args.out[z];
    const float* bias = args.bias[z];

#pragma unroll
    for (int i = 0; i < 4; ++i) {
#pragma unroll
        for (int j = 0; j < 8; ++j) {
            const int n = bn0 + wn + j * 16 + m16;
            const float bn_ = bias[n];
#pragma unroll
            for (int r = 0; r < 4; ++r) {
                const int m = bm0 + wm + i * 16 + quad * 4 + r;
                float v = acc[i][j][r] + bn_;
                // RoPE: pair partner (n^1) lives in lane^1 (same quad, same reg)
                const float part = __shfl_xor(v, 1, 64);
                if (rope) {
                    const int s = m & (S_LEN - 1);
                    const int p = (n & 127) >> 1;
                    const float cs = fcos[s * 64 + p];
                    const float sn = fsin[s * 64 + p];
                    v = (n & 1) ? (part * sn + v * cs) : (v * cs - part * sn);
                }
                out[(size_t)m * E_DIM + n] = f2bf(v);
            }
        }
    }
}

// ---------------- output projection GEMM (fp32 out + bias) ----------------
__global__ __launch_bounds__(256, 2)
void out_gemm(const u16t* __restrict__ sh, const u16t* __restrict__ wob,
              const float* __restrict__ bo, float* __restrict__ out) {
    __shared__ u16t As0[128 * 32], As1[128 * 32];
    __shared__ u16t Bs0[256 * 32], Bs1[256 * 32];
    facc4 acc[4][8];
    gemm_core(sh, wob, As0, As1, Bs0, Bs1, acc);

    const int t    = threadIdx.x;
    const int lane = t & 63;
    const int m16  = lane & 15;
    const int quad = lane >> 4;
    const int wid  = t >> 6;
    const int wm   = (wid & 1) * 64;
    const int wn   = (wid >> 1) * 128;
    const int bm0  = blockIdx.y * 128;
    const int bn0  = blockIdx.x * 256;

#pragma unroll
    for (int i = 0; i < 4; ++i) {
#pragma unroll
        for (int j = 0; j < 8; ++j) {
            const int n = bn0 + wn + j * 16 + m16;
            const float bn_ = bo[n];
#pragma unroll
            for (int r = 0; r < 4; ++r) {
                const int m = bm0 + wm + i * 16 + quad * 4 + r;
                out[(size_t)m * E_DIM + n] = acc[i][j][r] + bn_;
            }
        }
    }
}

// ---------------- per-token head attention, MFMA version ----------------
// One WAVE per token. S = Q.K^T via 4x mfma 16x16x32 (A-frag = Q rows,
// B-frag = K rows, loaded as coalesced 16B chunks from global). Softmax over
// g across 16-lane groups. P transposed through LDS into A-frag (K padded to
// 32 with zeros); PV via 8 MFMAs with V B-frags from an LDS-staged tile.
// Output scattered to shuffled layout sh[b][h*128 + s/16][(s%16)*128 + d].
__global__ __launch_bounds__(256)
void attn_kernel(const u16t* __restrict__ qb, const u16t* __restrict__ kb,
                 const u16t* __restrict__ vb, u16t* __restrict__ sh) {
    __shared__ u16t Vs[4][16 * 136];   // pad 136: 4-way worst on frag reads
    __shared__ u16t Pt[4][16 * 32];    // P in A-frag layout, cols 16..31 = 0

    const int t    = threadIdx.x;
    const int wid  = t >> 6;
    const int lane = t & 63;
    const int m16  = lane & 15;
    const int quad = lane >> 4;
    const int tk   = blockIdx.x * 4 + wid;
    const int b    = tk >> 11;
    const int s    = tk & (S_LEN - 1);
    const size_t row = (size_t)tk * E_DIM;

    // Q,K fragments straight from global (16B per lane per k-step)
    frag8 aq[4], ak[4];
    const u16t* qrow = qb + row + m16 * 128 + quad * 8;
    const u16t* krow = kb + row + m16 * 128 + quad * 8;
#pragma unroll
    for (int ks = 0; ks < 4; ++ks) {
        aq[ks] = *(const frag8*)(qrow + ks * 32);
        ak[ks] = *(const frag8*)(krow + ks * 32);
    }

    // V row -> LDS [16][136]
    u16t* vs = Vs[wid];
#pragma unroll
    for (int c = 0; c < 4; ++c) {
        const int e  = c * 512 + lane * 8;
        const int vr = e >> 7, vc = e & 127;
        *(uint4*)(vs + vr * 136 + vc) = *(const uint4*)(vb + row + e);
    }

    // scores
    facc4 sacc = facc4{0.f, 0.f, 0.f, 0.f};
#pragma unroll
    for (int ks = 0; ks < 4; ++ks)
        sacc = __builtin_amdgcn_mfma_f32_16x16x32_bf16(aq[ks], ak[ks], sacc, 0, 0, 0);

    // softmax over g (16 lanes of the same quad); lane holds rows h=quad*4+r at col g=m16
    float p[4], mx[4], sm[4];
#pragma unroll
    for (int r = 0; r < 4; ++r) { p[r] = sacc[r] * 0.08838834764831845f; mx[r] = p[r]; }
#pragma unroll
    for (int msk = 1; msk < 16; msk <<= 1)
#pragma unroll
        for (int r = 0; r < 4; ++r) mx[r] = fmaxf(mx[r], __shfl_xor(mx[r], msk, 64));
#pragma unroll
    for (int r = 0; r < 4; ++r) { p[r] = __expf(p[r] - mx[r]); sm[r] = p[r]; }
#pragma unroll
    for (int msk = 1; msk < 16; msk <<= 1)
#pragma unroll
        for (int r = 0; r < 4; ++r) sm[r] += __shfl_xor(sm[r], msk, 64);

    // P -> LDS in A-frag layout: Pt[h][g], h rows of 32 (cols 16..31 zero)
    u16t* pt = Pt[wid];
#pragma unroll
    for (int r = 0; r < 4; ++r)
        pt[(quad * 4 + r) * 32 + m16] = f2bf(p[r] / sm[r]);
    *(uint2*)(pt + m16 * 32 + 16 + quad * 4) = uint2{0u, 0u};   // zero pad

    __syncthreads();

    // A-frag of P: lane holds P[m16][quad*8+j]
    const frag8 aP = *(const frag8*)(pt + m16 * 32 + quad * 8);

    // PV: 8 d-blocks of 16; B-frag j: V[(quad*8+j)&15][dblk*16+m16]
    // (quads 2,3 read duplicate addresses of quads 0,1 -> broadcast; their
    //  products are zeroed by the K-padding in aP)
    facc4 oacc[8];
#pragma unroll
    for (int d = 0; d < 8; ++d) oacc[d] = facc4{0.f, 0.f, 0.f, 0.f};
#pragma unroll
    for (int dblk = 0; dblk < 8; ++dblk) {
        union { u16t u[8]; frag8 f; } bb;
#pragma unroll
        for (int j = 0; j < 8; ++j)
            bb.u[j] = vs[((quad * 8 + j) & 15) * 136 + dblk * 16 + m16];
        oacc[dblk] = __builtin_amdgcn_mfma_f32_16x16x32_bf16(aP, bb.f, oacc[dblk], 0, 0, 0);
    }

    // scatter to shuffled layout: lane holds out[h=quad*4+r][d=dblk*16+m16]
    const size_t base = ((size_t)b << 22) + (size_t)(s >> 4) * E_DIM
                      + (size_t)((s & 15) * 128);
#pragma unroll
    for (int dblk = 0; dblk < 8; ++dblk) {
        const int d = dblk * 16 + m16;
#pragma unroll
        for (int r = 0; r < 4; ++r) {
            const int h = quad * 4 + r;
            sh[base + ((size_t)h << 18) + d] = f2bf(oacc[dblk][r]);
        }
    }
}

// ---------------- launch ----------------
extern "C" void kernel_launch(void* const* d_in, const int* in_sizes, int n_in,
                              void* d_out, int out_size, void* d_ws, size_t ws_size,
                              hipStream_t stream) {
    const float* x    = (const float*)d_in[0];
    const float* fcos = (const float*)d_in[1];
    const float* fsin = (const float*)d_in[2];
    const float* wq   = (const float*)d_in[3];
    const float* bq   = (const float*)d_in[4];
    const float* wk   = (const float*)d_in[5];
    const float* bk   = (const float*)d_in[6];
    const float* wv   = (const float*)d_in[7];
    const float* bv   = (const float*)d_in[8];
    const float* wo   = (const float*)d_in[9];
    const float* bo   = (const float*)d_in[10];
    float* out = (float*)d_out;

    char* ws = (char*)d_ws;
    u16t* xb  = (u16t*)(ws);                      // 32 MB, reused as shuffled buf
    u16t* qb  = (u16t*)(ws + 33554432ull);
    u16t* kb  = (u16t*)(ws + 67108864ull);
    u16t* vb  = (u16t*)(ws + 100663296ull);
    u16t* wqb = (u16t*)(ws + 134217728ull);
    u16t* wkb = (u16t*)(ws + 142606336ull);
    u16t* wvb = (u16t*)(ws + 150994944ull);
    u16t* wob = (u16t*)(ws + 159383552ull);       // total 160 MB

    cvt_kernel<<<16384, 256, 0, stream>>>(x, xb, 4194304);
    cvt_kernel<<<4096, 256, 0, stream>>>(wq, wqb, 1048576);
    cvt_kernel<<<4096, 256, 0, stream>>>(wk, wkb, 1048576);
    cvt_kernel<<<4096, 256, 0, stream>>>(wv, wvb, 1048576);
    cvt_kernel<<<4096, 256, 0, stream>>>(wo, wob, 1048576);

    QkvArgs qa;
    qa.w[0] = wqb; qa.w[1] = wkb; qa.w[2] = wvb;
    qa.bias[0] = bq; qa.bias[1] = bk; qa.bias[2] = bv;
    qa.out[0] = qb; qa.out[1] = kb; qa.out[2] = vb;
    qkv_gemm<<<dim3(8, 64, 3), 256, 0, stream>>>(xb, qa, fcos, fsin);

    attn_kernel<<<2048, 256, 0, stream>>>(qb, kb, vb, xb);

    out_gemm<<<dim3(8, 64), 256, 0, stream>>>(xb, wob, bo, out);
}